// Round 6
// baseline (86.515 us; speedup 1.0000x reference)
//
#include <hip/hip_runtime.h>

// NEUROPULS unitary mesh, N=256 — R9: no global loads in the stage loop.
// R8 post-mortem: per-stage cost is ~750 cy INVARIANT to loop content
// (R0:130 VALU, R6:75, R8:55 VALU/stage all ~40 us). The fixed pole is the
// per-stage global load latency fully exposed each iteration (compiler
// drains vmem before first use; source-level distance-3 prefetch does not
// survive — the known HIP-compiler vmcnt-drain failure mode). 256 lockstep
// waves touch each new line simultaneously -> ~650-700 cy exposed.
// Fix: theta rows 1..128 = exactly 128 KiB -> bulk-stage into LDS once
// (prologue, throughput-pipelined), then the 128-stage serial loop is
// LDS+registers only: ds_read_b128 (distance-2, counted lgkmcnt; worst
// case ~120 cy, not 700) + off-chain sincos/prep (1 stage ahead) +
// on-chain mstep+crossing (verbatim from passing R6/R8).
// Collapsed operator (verified, R6/R8 passed):
//   [[E, G],[G, F]]  E=U*p0-W*p1, F=U*p1-W*p0, G=i*g*(p0+p1),
//   U=AT^2, W=AR^2, g=AT*AR.

__device__ __forceinline__ float dpp_up1(float x) {
    // lane n <- lane n-1 (wave_shr:1); lane 0 keeps old, masked later
    return __int_as_float(__builtin_amdgcn_update_dpp(
        __float_as_int(x), __float_as_int(x), 0x138, 0xf, 0xf, false));
}
__device__ __forceinline__ float dpp_dn1(float x) {
    // lane n <- lane n+1 (wave_shl:1); lane 63 keeps old, masked later
    return __int_as_float(__builtin_amdgcn_update_dpp(
        __float_as_int(x), __float_as_int(x), 0x130, 0xf, 0xf, false));
}

__device__ __forceinline__ void sincos4(float4 th, float sn[4], float cs[4]) {
    __sincosf(th.x, &sn[0], &cs[0]);
    __sincosf(th.y, &sn[1], &cs[1]);
    __sincosf(th.z, &sn[2], &cs[2]);
    __sincosf(th.w, &sn[3], &cs[3]);
}

// Per-stage collapsed-operator coefficients, 2 pairs per lane.
struct Coef {
    float Er[2], Ei[2], Fr[2], Fi[2], Gr[2], Gi[2];
};

__global__ __launch_bounds__(64, 1)
void neuropuls_mesh_kernel(const float* __restrict__ thetas,  // [130,256] fp32
                           float* __restrict__ out)           // re[65536] || im[65536]
{
    constexpr int N = 256;
    __shared__ float thlds[128 * N];   // 128 KiB: theta rows 1..128

    const int lane = threadIdx.x;   // 0..63
    const int col  = blockIdx.x;    // 0..255

    const float U  = 0.98f * 0.505f;                  // AT^2
    const float W  = 0.98f * 0.495f;                  // AR^2
    const float Gc = 0.98f * sqrtf(0.505f * 0.495f);  // AT*AR
    const float BT = sqrtf(0.98f * 0.01f);            // CR a*sqrt(CT)
    const float BR = sqrtf(0.98f * 0.99f);            // CR a*sqrt(1-CT) == thru

    // ---- bulk-stage theta[1..128] -> LDS (one-time, off the serial chain;
    //      compiler pipelines many loads+ds_writes in flight) ----
    {
        const float4* src = (const float4*)(thetas + N) + lane;  // row 1 onward
        float4*       dst = (float4*)thlds + lane;
        #pragma unroll 8
        for (int i = 0; i < 128; ++i)
            dst[i * 64] = src[i * 64];
    }
    // Single wave per block: LDS write->read ordering is enforced by the
    // compiler's lgkmcnt waits (same-array dependency); no barrier needed.

    float vr[4] = {0.f, 0.f, 0.f, 0.f};
    float vi[4] = {0.f, 0.f, 0.f, 0.f};

    // arch0 = diag(exp(i*theta[0]))  (global, one-time)
    {
        const float th0 = thetas[col];
        float s0, c0;
        __sincosf(th0, &s0, &c0);
        const int r0 = col - 4 * lane;
        if (0 <= r0 && r0 < 4) { vr[r0] = c0; vi[r0] = s0; }
    }

    auto prep4 = [&](float4 th, Coef& K) {
        float s[4], c[4];
        sincos4(th, s, c);
        #pragma unroll
        for (int p = 0; p < 2; ++p) {
            const float c0 = c[2 * p], c1 = c[2 * p + 1];
            const float s0 = s[2 * p], s1 = s[2 * p + 1];
            K.Er[p] = U * c0 - W * c1;   K.Ei[p] = U * s0 - W * s1;
            K.Fr[p] = U * c1 - W * c0;   K.Fi[p] = U * s1 - W * s0;
            K.Gr[p] = -Gc * (s0 + s1);   K.Gi[p] = Gc * (c0 + c1);
        }
    };

    // Collapsed MMI*diag(p)*MMI on pairs (0,1),(2,3): x'=E*x+G*y; y'=G*x+F*y
    auto mstep = [&](const Coef& K) {
        #pragma unroll
        for (int p = 0; p < 2; ++p) {
            const int x = 2 * p, y = 2 * p + 1;
            const float xr = vr[x], xi = vi[x], yr = vr[y], yi = vi[y];
            vr[x] = K.Er[p] * xr - K.Ei[p] * xi + K.Gr[p] * yr - K.Gi[p] * yi;
            vi[x] = K.Er[p] * xi + K.Ei[p] * xr + K.Gr[p] * yi + K.Gi[p] * yr;
            vr[y] = K.Gr[p] * xr - K.Gi[p] * xi + K.Fr[p] * yr - K.Fi[p] * yi;
            vi[y] = K.Gr[p] * xi + K.Gi[p] * xr + K.Fr[p] * yi + K.Fi[p] * yr;
        }
    };

    auto crossing = [&]() {
        float pv3r = dpp_up1(vr[3]);
        float pv3i = dpp_up1(vi[3]);
        float nv0r = dpp_dn1(vr[0]);
        float nv0i = dpp_dn1(vi[0]);
        {   // internal odd pair (4t+1, 4t+2)
            float xr = vr[1], xi = vi[1], yr = vr[2], yi = vi[2];
            vr[1] = BT * xr - BR * yi;  vi[1] = BT * xi + BR * yr;
            vr[2] = BT * yr - BR * xi;  vi[2] = BT * yi + BR * xr;
        }
        {   // pair (4t-1, 4t): lane 0 row 0 = thru
            float yr = vr[0], yi = vi[0];
            float nr = BT * yr - BR * pv3i;
            float ni = BT * yi + BR * pv3r;
            vr[0] = (lane == 0) ? BR * yr : nr;
            vi[0] = (lane == 0) ? BR * yi : ni;
        }
        {   // pair (4t+3, 4t+4): lane 63 row 255 = thru
            float xr = vr[3], xi = vi[3];
            float nr = BT * xr - BR * nv0i;
            float ni = BT * xi + BR * nv0r;
            vr[3] = (lane == 63) ? BR * xr : nr;
            vi[3] = (lane == 63) ? BR * xi : ni;
        }
    };

    // ---- software pipeline over LDS ----
    // invariant entering iter s: K = coefs(theta[s]); thA = theta[s+1];
    // tnext -> theta[s+2] in LDS.
    const float4* tl = (const float4*)thlds + lane;  // theta[1] slice
    Coef K;
    float4 thA;
    {
        float4 t1 = tl[0];          // theta[1]
        thA       = tl[64];         // theta[2]
        prep4(t1, K);
    }
    const float4* tnext = tl + 128; // theta[3]

    // crossing stages s = 1..126 (127th after the loop); 126 = 42*3
    #pragma unroll 3
    for (int s = 1; s <= 126; ++s) {
        float4 thB = tnext[0];      // theta[s+2] (<=128), ds_read, counted lgkm
        tnext += 64;
        Coef Kn;
        prep4(thA, Kn);             // coeffs for stage s+1, off-chain
        // ---- serial state chain ----
        mstep(K);
        crossing();
        // rotate (renamed by unroll 3)
        K = Kn; thA = thB;
    }

    // stage 127 (last crossing stage); K = coefs(theta[127])
    mstep(K);
    crossing();

    // stage 128: mstep only; thA = theta[128]
    {
        Coef KF;
        prep4(thA, KF);
        mstep(KF);
    }

    // final phase layer theta[129] (global, one-time)
    {
        float4 thF = *(const float4*)(thetas + 129 * N + 4 * lane);
        float sn[4], cs[4];
        sincos4(thF, sn, cs);
        #pragma unroll
        for (int j = 0; j < 4; ++j) {
            float r = vr[j], i = vi[j];
            vr[j] = cs[j] * r - sn[j] * i;
            vi[j] = cs[j] * i + sn[j] * r;
        }
    }

    // store PLANAR: real block then imag block, each row-major [row][col]
    #pragma unroll
    for (int j = 0; j < 4; ++j) {
        const int idx = (4 * lane + j) * N + col;
        out[idx]         = vr[j];
        out[N * N + idx] = vi[j];
    }
}

extern "C" void kernel_launch(void* const* d_in, const int* in_sizes, int n_in,
                              void* d_out, int out_size, void* d_ws, size_t ws_size,
                              hipStream_t stream)
{
    const float* thetas = (const float*)d_in[0];   // [130,256] fp32
    float* out = (float*)d_out;                    // planar: re[65536] || im[65536]
    (void)in_sizes; (void)n_in; (void)out_size; (void)d_ws; (void)ws_size;
    neuropuls_mesh_kernel<<<dim3(256), dim3(64), 0, stream>>>(thetas, out);
}